// Round 6
// baseline (1571.554 us; speedup 1.0000x reference)
//
#include <hip/hip_runtime.h>
#include <hip/hip_bf16.h>
#include <stdint.h>

// ---------------- constants ----------------
#define DIMC 512
#define HEADS 16
#define HEAD_DIM 32
#define NTOK 49            // tokens per window (7x7)
#define SCALE 0.17677669529663687f   // 1/sqrt(32)

typedef unsigned short u16;
typedef short bf16x8 __attribute__((ext_vector_type(8)));
typedef float f32x4 __attribute__((ext_vector_type(4)));
typedef u16 u16x4 __attribute__((ext_vector_type(4)));
typedef u16 u16x8 __attribute__((ext_vector_type(8)));

#define MFMA16(a, b, c) __builtin_amdgcn_mfma_f32_16x16x32_bf16((a), (b), (c), 0, 0, 0)

__device__ __forceinline__ u16 f2bf(float f) {
  __hip_bfloat16 h = __float2bfloat16(f);   // RNE
  u16 u;
  __builtin_memcpy(&u, &h, 2);
  return u;
}

__device__ __forceinline__ float bf2f(u16 u) {
  const uint32_t b = ((uint32_t)u) << 16;
  float f;
  __builtin_memcpy(&f, &b, 4);
  return f;
}

// async global->LDS, 16 bytes per lane (wave-uniform LDS base + lane*16)
__device__ __forceinline__ void gld16(const void* g, void* l) {
  __builtin_amdgcn_global_load_lds(
      (const __attribute__((address_space(1))) uint32_t*)g,
      (__attribute__((address_space(3))) uint32_t*)l, 16, 0, 0);
}

// ---------------- fp32 -> bf16 convert (grid-stride, 8 elems/thread/iter) ----
__global__ void cvt_f32_bf16(const float* __restrict__ in, u16* __restrict__ out, int n) {
  const int stride = gridDim.x * blockDim.x;
  for (int i = blockIdx.x * blockDim.x + threadIdx.x; i * 8 < n; i += stride) {
    const float4 v0 = ((const float4*)(in + i * 8))[0];
    const float4 v1 = ((const float4*)(in + i * 8))[1];
    u16x8 r;
    r[0] = f2bf(v0.x); r[1] = f2bf(v0.y); r[2] = f2bf(v0.z); r[3] = f2bf(v0.w);
    r[4] = f2bf(v1.x); r[5] = f2bf(v1.y); r[6] = f2bf(v1.z); r[7] = f2bf(v1.w);
    *(u16x8*)(out + i * 8) = r;
  }
}

// ---- bias+mask precompute, C-FRAGMENT order, bf16: [wm][h][i][j][lane][r] ----
__global__ void biasmask_kernel(const float* __restrict__ table, const float* __restrict__ mask,
                                u16* __restrict__ bm) {
  const int wm = blockIdx.x >> 4;   // 0..63
  const int h  = blockIdx.x & 15;   // 0..15
  for (int e = threadIdx.x; e < 4096; e += 256) {
    const int r = e & 3, lane = (e >> 2) & 63, fj = (e >> 8) & 3, fi = e >> 10;
    const int row = fi * 16 + (lane >> 4) * 4 + r;
    const int col = fj * 16 + (lane & 15);
    float v;
    if (row < NTOK && col < NTOK) {
      const int yi = row / 7, xi = row % 7, yj = col / 7, xj = col % 7;
      const int idx = (yi - yj + 6) * 13 + (xi - xj + 6);
      v = table[idx * HEADS + h] + mask[wm * (NTOK * NTOK) + row * NTOK + col];
    } else {
      v = -1e30f;   // pad -> exp == exact 0
    }
    bm[(size_t)blockIdx.x * 4096 + e] = f2bf(v);
  }
}

// ---------------- GEMM: C[M,N] = A[M,K] @ B[N,K]^T + bias (all bf16 in) ------
// R2-proven datapath (tile 128x128, BK=64, 4 waves 2x2, chunk-XOR swizzle,
// XCD-bijective blockIdx) + T3/T4 pipelining: TRIPLE-buffered LDS, raw
// s_barrier, counted vmcnt (16 -> 8 -> 0) so 2 K-tiles of loads stay in
// flight across barriers (never drained in steady state).
template<bool OUT_BF16, bool QKV_SCALE>
__global__ void gemm_bf16(const u16* __restrict__ Ap, const u16* __restrict__ Bp,
                          const float* __restrict__ bias, void* __restrict__ Cp,
                          int M, int N, int K, int nxt) {
  __shared__ u16 As[3][128 * 64];
  __shared__ u16 Bs[3][128 * 64];
  const int t = threadIdx.x;
  const int lane = t & 63;
  // XCD swizzle: physical lin -> logical l so each XCD walks n-fast (A reuse in L2)
  const int q = gridDim.x >> 3;
  const int lin = blockIdx.x;
  const int l = (lin & 7) * q + (lin >> 3);
  const int bm0 = (l / nxt) * 128;
  const int bn0 = (l % nxt) * 128;
  const int wv = t >> 6, wr = wv >> 1, wc = wv & 1;
  const int lr = lane & 15, lg = lane >> 4;

  f32x4 acc[4][4] = {};

  // staging geometry: 1024 16B-chunks per operand per K-tile, 4 per thread
  int srow[4], soff[4];
#pragma unroll
  for (int k = 0; k < 4; ++k) {
    const int c = t + 256 * k;
    srow[k] = c >> 3;
    soff[k] = (((c & 7) ^ (srow[k] & 7)) * 8);  // swizzled source column
  }

  const int nK = K >> 6;

#define STAGE(KT, B)                                                            \
  {                                                                             \
    const int k0_ = (KT) << 6;                                                  \
    _Pragma("unroll")                                                           \
    for (int k = 0; k < 4; ++k) {                                               \
      const int c = t + 256 * k;                                                \
      gld16(Ap + (size_t)(bm0 + srow[k]) * K + k0_ + soff[k], &As[B][c * 8]);   \
      gld16(Bp + (size_t)(bn0 + srow[k]) * K + k0_ + soff[k], &Bs[B][c * 8]);   \
    }                                                                           \
  }

  // prologue: two K-tiles in flight
  STAGE(0, 0);
  STAGE(1, 1);

  for (int kt = 0; kt < nK; ++kt) {
    // stage tile kt+2 into the buffer freed at the end of iter kt-1
    if (kt + 2 < nK) STAGE(kt + 2, (kt + 2) % 3);
    // wait ONLY for tile kt's 8 loads (16 = tiles kt+1,kt+2 stay in flight)
    if (kt + 2 < nK)      asm volatile("s_waitcnt vmcnt(16)" ::: "memory");
    else if (kt + 1 < nK) asm volatile("s_waitcnt vmcnt(8)" ::: "memory");
    else                  asm volatile("s_waitcnt vmcnt(0)" ::: "memory");
    __builtin_amdgcn_s_barrier();          // all waves: tile kt resident
    __builtin_amdgcn_sched_barrier(0);     // pin: no ds_read hoisted above

    const u16* Asb = &As[kt % 3][0];
    const u16* Bsb = &Bs[kt % 3][0];
#pragma unroll
    for (int kk = 0; kk < 2; ++kk) {
      bf16x8 af[4], bfr[4];
#pragma unroll
      for (int i = 0; i < 4; ++i) {
        const int row = wr * 64 + i * 16 + lr;
        af[i] = *(const bf16x8*)&Asb[row * 64 + (((kk * 4 + lg) ^ (row & 7)) << 3)];
      }
#pragma unroll
      for (int j = 0; j < 4; ++j) {
        const int row = wc * 64 + j * 16 + lr;
        bfr[j] = *(const bf16x8*)&Bsb[row * 64 + (((kk * 4 + lg) ^ (row & 7)) << 3)];
      }
      __builtin_amdgcn_s_setprio(1);
#pragma unroll
      for (int i = 0; i < 4; ++i)
#pragma unroll
        for (int j = 0; j < 4; ++j)
          acc[i][j] = MFMA16(af[i], bfr[j], acc[i][j]);
      __builtin_amdgcn_s_setprio(0);
    }
    __builtin_amdgcn_sched_barrier(0);     // keep reads/MFMA inside the window
    __builtin_amdgcn_s_barrier();          // all waves done reading buf kt%3
  }
#undef STAGE

  // epilogue: D row = (lane>>4)*4 + r, col = lane&15 (m89-verified layout)
#pragma unroll
  for (int j = 0; j < 4; ++j) {
    const int col = bn0 + wc * 64 + j * 16 + lr;
    const float bv = bias[col];
    const float sc = (QKV_SCALE && col < DIMC) ? SCALE : 1.0f;
#pragma unroll
    for (int i = 0; i < 4; ++i) {
      const int row0 = bm0 + wr * 64 + i * 16 + lg * 4;
#pragma unroll
      for (int r = 0; r < 4; ++r) {
        const float val = (acc[i][j][r] + bv) * sc;
        if (OUT_BF16)
          ((u16*)Cp)[(size_t)(row0 + r) * N + col] = f2bf(val);
        else
          ((float*)Cp)[(size_t)(row0 + r) * N + col] = val;
      }
    }
  }
}

// ---------------- fused window attention (v2, unchanged from R5) ----------------
__global__ void attn_win(const u16* __restrict__ qkv, const u16* __restrict__ bmfrag,
                         u16* __restrict__ aout) {
  __shared__ u16 P[4][64 * 64];    // per-wave P tile, chunk-XOR swizzled
  __shared__ u16 Vs[4][64 * 40];   // per-wave V tile, row-major stride 40
  const int t = threadIdx.x, lane = t & 63, wv = t >> 6;
  const int lr = lane & 15, lg = lane >> 4;
  const int w = blockIdx.x >> 2;
  const int h = ((blockIdx.x & 3) << 2) + wv;
  const size_t base = (size_t)w * NTOK * 1536 + h * HEAD_DIM;

  // acc init = bias+mask fragments (bf16, fragment-ordered, 8B/lane)
  const u16* bmp = bmfrag + (((size_t)(w & 63) * 16 + h) << 12);
  f32x4 s[4][4];
#pragma unroll
  for (int i = 0; i < 4; ++i)
#pragma unroll
    for (int j = 0; j < 4; ++j) {
      const u16x4 b4 = *(const u16x4*)&bmp[((i * 4 + j) * 64 + lane) * 4];
#pragma unroll
      for (int r = 0; r < 4; ++r) s[i][j][r] = bf2f(b4[r]);
    }

  const bf16x8 zf = {};
  bf16x8 qf[4], kf[4];
#pragma unroll
  for (int i = 0; i < 4; ++i) {
    const int row = i * 16 + lr;
    const size_t roff = base + (size_t)row * 1536 + lg * 8;
    qf[i] = (row < NTOK) ? *(const bf16x8*)&qkv[roff] : zf;          // Q(row, d..)
    kf[i] = (row < NTOK) ? *(const bf16x8*)&qkv[roff + DIMC] : zf;   // K(row, d..)
  }

  // issue V loads early (coalesced 16B); latency hides under QK^T
  u16x8 vreg[4];
  const u16x8 vz = {};
#pragma unroll
  for (int it = 0; it < 4; ++it) {
    const int k = it * 16 + (lane >> 2);
    const int seg = lane & 3;
    vreg[it] = (k < NTOK) ? *(const u16x8*)&qkv[base + 2 * DIMC + (size_t)k * 1536 + seg * 8]
                          : vz;
  }

  __builtin_amdgcn_s_setprio(1);
#pragma unroll
  for (int i = 0; i < 4; ++i)
#pragma unroll
    for (int j = 0; j < 4; ++j)
      s[i][j] = MFMA16(qf[i], kf[j], s[i][j]);   // S = (Q*scale)K^T + bias + mask
  __builtin_amdgcn_s_setprio(0);

  // park V in LDS (per-wave slice)
  u16* Vsw = &Vs[wv][0];
#pragma unroll
  for (int it = 0; it < 4; ++it) {
    const int k = it * 16 + (lane >> 2);
    const int seg = lane & 3;
    *(u16x8*)&Vsw[k * 40 + seg * 8] = vreg[it];
  }

  // P = exp(S) (unnormalized) -> LDS bf16, C/D-layout scatter, chunk-XOR swizzle
  u16* Pw = &P[wv][0];
#pragma unroll
  for (int i = 0; i < 4; ++i)
#pragma unroll
    for (int r = 0; r < 4; ++r) {
      const int ii = i * 16 + lg * 4 + r;
#pragma unroll
      for (int j = 0; j < 4; ++j) {
        const int jj = j * 16 + lr;
        Pw[ii * 64 + (((jj >> 3) ^ (ii & 7)) << 3) + (jj & 7)] = f2bf(__expf(s[i][j][r]));
      }
    }

  // PV + row-sum: out[i][d] = sum_k P[i][k] V[k][d]; osum[i] = sum_k P[i][k]
  bf16x8 ones;
#pragma unroll
  for (int e = 0; e < 8; ++e) ones[e] = (short)0x3F80;  // bf16 1.0
  f32x4 o[4][2] = {};
  f32x4 osum[4] = {};
#pragma unroll
  for (int ks = 0; ks < 2; ++ks) {
    bf16x8 vf[2];
#pragma unroll
    for (int dn = 0; dn < 2; ++dn) {
#pragma unroll
      for (int e = 0; e < 8; ++e) {
        const int kk = ks * 32 + lg * 8 + e;
        vf[dn][e] = (short)Vsw[kk * 40 + dn * 16 + lr];
      }
    }
    __builtin_amdgcn_s_setprio(1);
#pragma unroll
    for (int i = 0; i < 4; ++i) {
      const int row = i * 16 + lr;
      const bf16x8 pa = *(const bf16x8*)&Pw[row * 64 + (((ks * 4 + lg) ^ (row & 7)) << 3)];
#pragma unroll
      for (int dn = 0; dn < 2; ++dn)
        o[i][dn] = MFMA16(pa, vf[dn], o[i][dn]);
      osum[i] = MFMA16(pa, ones, osum[i]);     // row-sum in C-layout
    }
    __builtin_amdgcn_s_setprio(0);
  }

  // store attention output (normalize here) -> [token][h*32+d] bf16
#pragma unroll
  for (int i = 0; i < 4; ++i)
#pragma unroll
    for (int r = 0; r < 4; ++r) {
      const int row = i * 16 + lg * 4 + r;
      if (row < NTOK) {
        const float rinv = __builtin_amdgcn_rcpf(osum[i][r]);
        const size_t ob = ((size_t)w * NTOK + row) * DIMC + h * HEAD_DIM;
#pragma unroll
        for (int dn = 0; dn < 2; ++dn)
          aout[ob + dn * 16 + lr] = f2bf(o[i][dn][r] * rinv);
      }
    }
}

// ---------------- launch ----------------
extern "C" void kernel_launch(void* const* d_in, const int* in_sizes, int n_in,
                              void* d_out, int out_size, void* d_ws, size_t ws_size,
                              hipStream_t stream) {
  const float* x      = (const float*)d_in[0];   // (4096,49,512)
  const float* mask   = (const float*)d_in[1];   // (64,49,49)
  const float* qkv_w  = (const float*)d_in[2];   // (1536,512)
  const float* qkv_b  = (const float*)d_in[3];   // (1536,)
  const float* table  = (const float*)d_in[4];   // (169,16)
  const float* proj_w = (const float*)d_in[5];   // (512,512)
  const float* proj_b = (const float*)d_in[6];   // (512,)
  float* out = (float*)d_out;

  const int M = 4096 * NTOK;   // 200704

  char* ws = (char*)d_ws;
  u16*   qkv_bf   = (u16*)ws;                         // 200704*1536*2 = 616,562,688
  u16*   wqkv_bf  = (u16*)(ws + 616562688ull);        // 1536*512*2    = 1,572,864
  u16*   wproj_bf = (u16*)(ws + 618135552ull);        // 512*512*2     = 524,288
  u16*   biasmask = (u16*)(ws + 618659840ull);        // 1024*4096*2   = 8,388,608
  // x_bf and attn_bf SHARE this region (disjoint lifetimes, same size):
  u16*   x_bf     = (u16*)(ws + 627048448ull);        // 200704*512*2  = 205,520,896
  u16*   attn_bf  = x_bf;
  // total 832,569,344 bytes

  cvt_f32_bf16<<<768, 256, 0, stream>>>(qkv_w, wqkv_bf, 1536 * 512);
  cvt_f32_bf16<<<256, 256, 0, stream>>>(proj_w, wproj_bf, 512 * 512);
  biasmask_kernel<<<1024, 256, 0, stream>>>(table, mask, biasmask);
  cvt_f32_bf16<<<1792, 256, 0, stream>>>(x, x_bf, M * DIMC);

  // QKV GEMM: (M,1536,512); grid 1568*12 = 18816 (%8==0)
  gemm_bf16<true, true><<<1568 * 12, 256, 0, stream>>>(
      x_bf, wqkv_bf, qkv_b, qkv_bf, M, 1536, 512, 12);

  attn_win<<<4096 * 4, 256, 0, stream>>>(qkv_bf, biasmask, attn_bf);

  // proj GEMM: (M,512,512); grid 1568*4 = 6272 (%8==0)
  gemm_bf16<false, false><<<1568 * 4, 256, 0, stream>>>(
      attn_bf, wproj_bf, proj_b, out, M, 512, 512, 4);
}

// Round 7
// 983.809 us; speedup vs baseline: 1.5974x; 1.5974x over previous
//
#include <hip/hip_runtime.h>
#include <hip/hip_bf16.h>
#include <stdint.h>

// ---------------- constants ----------------
#define DIMC 512
#define HEADS 16
#define HEAD_DIM 32
#define NTOK 49            // tokens per window (7x7)
#define SCALE 0.17677669529663687f   // 1/sqrt(32)

typedef unsigned short u16;
typedef short bf16x8 __attribute__((ext_vector_type(8)));
typedef float f32x4 __attribute__((ext_vector_type(4)));
typedef u16 u16x4 __attribute__((ext_vector_type(4)));
typedef u16 u16x8 __attribute__((ext_vector_type(8)));

#define MFMA16(a, b, c) __builtin_amdgcn_mfma_f32_16x16x32_bf16((a), (b), (c), 0, 0, 0)

__device__ __forceinline__ u16 f2bf(float f) {
  __hip_bfloat16 h = __float2bfloat16(f);   // RNE
  u16 u;
  __builtin_memcpy(&u, &h, 2);
  return u;
}

__device__ __forceinline__ float bf2f(u16 u) {
  const uint32_t b = ((uint32_t)u) << 16;
  float f;
  __builtin_memcpy(&f, &b, 4);
  return f;
}

// async global->LDS, 16 bytes per lane (wave-uniform LDS base + lane*16)
__device__ __forceinline__ void gld16(const void* g, void* l) {
  __builtin_amdgcn_global_load_lds(
      (const __attribute__((address_space(1))) uint32_t*)g,
      (__attribute__((address_space(3))) uint32_t*)l, 16, 0, 0);
}

// ---------------- fp32 -> bf16 convert (grid-stride, 8 elems/thread/iter) ----
__global__ void cvt_f32_bf16(const float* __restrict__ in, u16* __restrict__ out, int n) {
  const int stride = gridDim.x * blockDim.x;
  for (int i = blockIdx.x * blockDim.x + threadIdx.x; i * 8 < n; i += stride) {
    const float4 v0 = ((const float4*)(in + i * 8))[0];
    const float4 v1 = ((const float4*)(in + i * 8))[1];
    u16x8 r;
    r[0] = f2bf(v0.x); r[1] = f2bf(v0.y); r[2] = f2bf(v0.z); r[3] = f2bf(v0.w);
    r[4] = f2bf(v1.x); r[5] = f2bf(v1.y); r[6] = f2bf(v1.z); r[7] = f2bf(v1.w);
    *(u16x8*)(out + i * 8) = r;
  }
}

// ---- bias+mask precompute, C-FRAGMENT order, bf16: [wm][h][i][j][lane][r] ----
__global__ void biasmask_kernel(const float* __restrict__ table, const float* __restrict__ mask,
                                u16* __restrict__ bm) {
  const int wm = blockIdx.x >> 4;   // 0..63
  const int h  = blockIdx.x & 15;   // 0..15
  for (int e = threadIdx.x; e < 4096; e += 256) {
    const int r = e & 3, lane = (e >> 2) & 63, fj = (e >> 8) & 3, fi = e >> 10;
    const int row = fi * 16 + (lane >> 4) * 4 + r;
    const int col = fj * 16 + (lane & 15);
    float v;
    if (row < NTOK && col < NTOK) {
      const int yi = row / 7, xi = row % 7, yj = col / 7, xj = col % 7;
      const int idx = (yi - yj + 6) * 13 + (xi - xj + 6);
      v = table[idx * HEADS + h] + mask[wm * (NTOK * NTOK) + row * NTOK + col];
    } else {
      v = -1e30f;   // pad -> exp == exact 0
    }
    bm[(size_t)blockIdx.x * 4096 + e] = f2bf(v);
  }
}

// ---------------- GEMM: C[M,N] = A[M,K] @ B[N,K]^T + bias (all bf16 in) ------
// R2-PROVEN structure, FROZEN: 128x128 tile, BK=64, 4 waves (2x2 of 64x64),
// single-buffer LDS, gld16 staging with source-side chunk-XOR swizzle
// (0 conflicts measured), XCD-bijective blockIdx. 435 us / MfmaUtil 32%.
// Three pipelining attempts (R3 drain-once, R4 fused-A, R6 triple-buffer)
// all regressed via occupancy loss -- do not touch.
template<bool OUT_BF16, bool QKV_SCALE>
__global__ void gemm_bf16(const u16* __restrict__ Ap, const u16* __restrict__ Bp,
                          const float* __restrict__ bias, void* __restrict__ Cp,
                          int M, int N, int K, int nxt) {
  __shared__ u16 As[128 * 64];
  __shared__ u16 Bs[128 * 64];
  const int t = threadIdx.x;
  const int lane = t & 63;
  // XCD swizzle: physical lin -> logical l so each XCD walks n-fast (A reuse in L2)
  const int q = gridDim.x >> 3;
  const int lin = blockIdx.x;
  const int l = (lin & 7) * q + (lin >> 3);
  const int bm0 = (l / nxt) * 128;
  const int bn0 = (l % nxt) * 128;
  const int wv = t >> 6, wr = wv >> 1, wc = wv & 1;
  const int lr = lane & 15, lg = lane >> 4;

  f32x4 acc[4][4] = {};

  // staging geometry: 1024 16B-chunks per tile, 4 per thread (c = t + 256k)
  int soff[4];  // swizzled source column (elements)
#pragma unroll
  for (int k = 0; k < 4; ++k) {
    const int c = t + 256 * k;
    const int row = c >> 3, sub = c & 7;
    soff[k] = ((sub ^ (row & 7)) * 8);
  }

  const int nK = K >> 6;
  for (int kt = 0; kt < nK; ++kt) {
    const int k0 = kt << 6;
    __syncthreads();  // previous compute done; LDS safe to overwrite
#pragma unroll
    for (int k = 0; k < 4; ++k) {
      const int c = t + 256 * k;
      const int row = c >> 3;
      gld16(Ap + (size_t)(bm0 + row) * K + k0 + soff[k], As + c * 8);
      gld16(Bp + (size_t)(bn0 + row) * K + k0 + soff[k], Bs + c * 8);
    }
    __syncthreads();  // drains vmcnt(0): tiles ready

#pragma unroll
    for (int kk = 0; kk < 2; ++kk) {
      bf16x8 af[4], bfr[4];
#pragma unroll
      for (int i = 0; i < 4; ++i) {
        const int row = wr * 64 + i * 16 + lr;
        af[i] = *(const bf16x8*)&As[row * 64 + (((kk * 4 + lg) ^ (row & 7)) << 3)];
      }
#pragma unroll
      for (int j = 0; j < 4; ++j) {
        const int row = wc * 64 + j * 16 + lr;
        bfr[j] = *(const bf16x8*)&Bs[row * 64 + (((kk * 4 + lg) ^ (row & 7)) << 3)];
      }
#pragma unroll
      for (int i = 0; i < 4; ++i)
#pragma unroll
        for (int j = 0; j < 4; ++j)
          acc[i][j] = MFMA16(af[i], bfr[j], acc[i][j]);
    }
  }

  // epilogue: D row = (lane>>4)*4 + r, col = lane&15 (m89-verified layout)
#pragma unroll
  for (int j = 0; j < 4; ++j) {
    const int col = bn0 + wc * 64 + j * 16 + lr;
    const float bv = bias[col];
    const float sc = (QKV_SCALE && col < DIMC) ? SCALE : 1.0f;
#pragma unroll
    for (int i = 0; i < 4; ++i) {
      const int row0 = bm0 + wr * 64 + i * 16 + lg * 4;
#pragma unroll
      for (int r = 0; r < 4; ++r) {
        const float val = (acc[i][j][r] + bv) * sc;
        if (OUT_BF16)
          ((u16*)Cp)[(size_t)(row0 + r) * N + col] = f2bf(val);
        else
          ((float*)Cp)[(size_t)(row0 + r) * N + col] = val;
      }
    }
  }
}

// ---------------- fused window attention (v3) ----------------
// 1 wave per (window, head). qkv: [B_*49][1536] bf16 (q scaled already).
// v2's arithmetic (bias-frag acc-init, no-max softmax with -1e30 pad,
// ones-column MFMA row-sum, deferred 1/sum) + v1's lean memory path:
// NO V LDS staging (direct global B-frag loads, issued early) -> LDS 32 KB
// -> 5 blocks/CU (TLP is what this latency-bound kernel lives on).
__global__ void attn_win(const u16* __restrict__ qkv, const u16* __restrict__ bmfrag,
                         u16* __restrict__ aout) {
  __shared__ u16 P[4][64 * 64];    // per-wave P tile, chunk-XOR swizzled
  const int t = threadIdx.x, lane = t & 63, wv = t >> 6;
  const int lr = lane & 15, lg = lane >> 4;
  const int w = blockIdx.x >> 2;
  const int h = ((blockIdx.x & 3) << 2) + wv;
  const size_t base = (size_t)w * NTOK * 1536 + h * HEAD_DIM;

  // acc init = bias+mask fragments (bf16, fragment-ordered, 8B/lane)
  const u16* bmp = bmfrag + (((size_t)(w & 63) * 16 + h) << 12);
  f32x4 s[4][4];
#pragma unroll
  for (int i = 0; i < 4; ++i)
#pragma unroll
    for (int j = 0; j < 4; ++j) {
      const u16x4 b4 = *(const u16x4*)&bmp[((i * 4 + j) * 64 + lane) * 4];
#pragma unroll
      for (int r = 0; r < 4; ++r) s[i][j][r] = bf2f(b4[r]);
    }

  const bf16x8 zf = {};
  bf16x8 qf[4], kf[4];
#pragma unroll
  for (int i = 0; i < 4; ++i) {
    const int row = i * 16 + lr;
    const size_t roff = base + (size_t)row * 1536 + lg * 8;
    qf[i] = (row < NTOK) ? *(const bf16x8*)&qkv[roff] : zf;          // Q(row, d..)
    kf[i] = (row < NTOK) ? *(const bf16x8*)&qkv[roff + DIMC] : zf;   // K(row, d..)
  }

  __builtin_amdgcn_s_setprio(1);
#pragma unroll
  for (int i = 0; i < 4; ++i)
#pragma unroll
    for (int j = 0; j < 4; ++j)
      s[i][j] = MFMA16(qf[i], kf[j], s[i][j]);   // S = (Q*scale)K^T + bias + mask
  __builtin_amdgcn_s_setprio(0);

  // V as B-fragments, direct from global (R2-proven); issue EARLY so the
  // ~300cy latency hides under exp + P-write. Clamp pad rows (P==0 there;
  // also avoids OOB read past the last window).
  bf16x8 vf[2][2];
#pragma unroll
  for (int ks = 0; ks < 2; ++ks)
#pragma unroll
    for (int dn = 0; dn < 2; ++dn)
#pragma unroll
      for (int e = 0; e < 8; ++e) {
        int kk = ks * 32 + lg * 8 + e;
        kk = kk < NTOK ? kk : 0;
        vf[ks][dn][e] = (short)qkv[base + 2 * DIMC + (size_t)kk * 1536 + dn * 16 + lr];
      }

  // P = exp(S) (unnormalized) -> LDS bf16, C/D-layout scatter, chunk-XOR swizzle
  u16* Pw = &P[wv][0];
#pragma unroll
  for (int i = 0; i < 4; ++i)
#pragma unroll
    for (int r = 0; r < 4; ++r) {
      const int ii = i * 16 + lg * 4 + r;
#pragma unroll
      for (int j = 0; j < 4; ++j) {
        const int jj = j * 16 + lr;
        Pw[ii * 64 + (((jj >> 3) ^ (ii & 7)) << 3) + (jj & 7)] = f2bf(__expf(s[i][j][r]));
      }
    }

  // PV + row-sum: out[i][d] = sum_k P[i][k] V[k][d]; osum[i] = sum_k P[i][k]
  bf16x8 ones;
#pragma unroll
  for (int e = 0; e < 8; ++e) ones[e] = (short)0x3F80;  // bf16 1.0
  f32x4 o[4][2] = {};
  f32x4 osum[4] = {};
#pragma unroll
  for (int ks = 0; ks < 2; ++ks) {
    __builtin_amdgcn_s_setprio(1);
#pragma unroll
    for (int i = 0; i < 4; ++i) {
      const int row = i * 16 + lr;
      const bf16x8 pa = *(const bf16x8*)&Pw[row * 64 + (((ks * 4 + lg) ^ (row & 7)) << 3)];
#pragma unroll
      for (int dn = 0; dn < 2; ++dn)
        o[i][dn] = MFMA16(pa, vf[ks][dn], o[i][dn]);
      osum[i] = MFMA16(pa, ones, osum[i]);     // row-sum in C-layout
    }
    __builtin_amdgcn_s_setprio(0);
  }

  // store attention output (normalize here) -> [token][h*32+d] bf16
#pragma unroll
  for (int i = 0; i < 4; ++i)
#pragma unroll
    for (int r = 0; r < 4; ++r) {
      const int row = i * 16 + lg * 4 + r;
      if (row < NTOK) {
        const float rinv = __builtin_amdgcn_rcpf(osum[i][r]);
        const size_t ob = ((size_t)w * NTOK + row) * DIMC + h * HEAD_DIM;
#pragma unroll
        for (int dn = 0; dn < 2; ++dn)
          aout[ob + dn * 16 + lr] = f2bf(o[i][dn][r] * rinv);
      }
    }
}

// ---------------- launch ----------------
extern "C" void kernel_launch(void* const* d_in, const int* in_sizes, int n_in,
                              void* d_out, int out_size, void* d_ws, size_t ws_size,
                              hipStream_t stream) {
  const float* x      = (const float*)d_in[0];   // (4096,49,512)
  const float* mask   = (const float*)d_in[1];   // (64,49,49)
  const float* qkv_w  = (const float*)d_in[2];   // (1536,512)
  const float* qkv_b  = (const float*)d_in[3];   // (1536,)
  const float* table  = (const float*)d_in[4];   // (169,16)
  const float* proj_w = (const float*)d_in[5];   // (512,512)
  const float* proj_b = (const float*)d_in[6];   // (512,)
  float* out = (float*)d_out;

  const int M = 4096 * NTOK;   // 200704

  char* ws = (char*)d_ws;
  u16*   qkv_bf   = (u16*)ws;                         // 200704*1536*2 = 616,562,688
  u16*   wqkv_bf  = (u16*)(ws + 616562688ull);        // 1536*512*2    = 1,572,864
  u16*   wproj_bf = (u16*)(ws + 618135552ull);        // 512*512*2     = 524,288
  u16*   biasmask = (u16*)(ws + 618659840ull);        // 1024*4096*2   = 8,388,608
  // x_bf and attn_bf SHARE this region (disjoint lifetimes, same size):
  u16*   x_bf     = (u16*)(ws + 627048448ull);        // 200704*512*2  = 205,520,896
  u16*   attn_bf  = x_bf;
  // total 832,569,344 bytes

  cvt_f32_bf16<<<768, 256, 0, stream>>>(qkv_w, wqkv_bf, 1536 * 512);
  cvt_f32_bf16<<<256, 256, 0, stream>>>(proj_w, wproj_bf, 512 * 512);
  biasmask_kernel<<<1024, 256, 0, stream>>>(table, mask, biasmask);
  cvt_f32_bf16<<<1792, 256, 0, stream>>>(x, x_bf, M * DIMC);

  // QKV GEMM: (M,1536,512); grid 1568*12 = 18816 (%8==0)
  gemm_bf16<true, true><<<1568 * 12, 256, 0, stream>>>(
      x_bf, wqkv_bf, qkv_b, qkv_bf, M, 1536, 512, 12);

  attn_win<<<4096 * 4, 256, 0, stream>>>(qkv_bf, biasmask, attn_bf);

  // proj GEMM: (M,512,512); grid 1568*4 = 6272 (%8==0)
  gemm_bf16<false, false><<<1568 * 4, 256, 0, stream>>>(
      attn_bf, wproj_bf, proj_b, out, M, 512, 512, 4);
}